// Round 6
// baseline (788.226 us; speedup 1.0000x reference)
//
#include <hip/hip_runtime.h>
#include <hip/hip_bf16.h>
#include <cstdint>

typedef __bf16 bf16;
typedef __attribute__((ext_vector_type(8))) __bf16 bf16x8;
typedef __attribute__((ext_vector_type(4))) float f32x4;

constexpr int DIM = 384;
constexpr int HEAD_DIM = 48;
constexpr int ADLA_N = 343;
constexpr int NTOK = 2744;        // 14^3
constexpr int BATCH = 8;
constexpr int MTOT = BATCH * NTOK; // 21952
constexpr float SCALE = 0.14433756729740643f; // 48^-0.5
constexpr int B1W = 2816;          // bias1 padded width (22*128)
constexpr int B2W = 384;           // bias2 padded width (3*128)
constexpr int ADV_W = 352;         // adla_v^T padded cols

// ---------------- weight transpose (f32 in -> bf16 out) -------------------------
__global__ void transpose_weights(const float* __restrict__ Wq,
                                  const float* __restrict__ Wkv,
                                  const float* __restrict__ Wproj,
                                  bf16* __restrict__ WTall,
                                  bf16* __restrict__ WprojT) {
  int idx = blockIdx.x * 256 + threadIdx.x;
  const int total1 = 1152 * 384;
  if (idx < total1) {
    int j = idx / 384, k = idx % 384;
    WTall[idx] = (bf16)((j < 384) ? Wq[k * 384 + j] : Wkv[k * 768 + (j - 384)]);
  } else {
    int i2 = idx - total1;
    if (i2 < 384 * 384) {
      int j = i2 / 384, k = i2 % 384;
      WprojT[i2] = (bf16)Wproj[k * 384 + j];
    }
  }
}

// ---------------- trilinear interp helpers (out 14 from in 7) ------------------
__device__ __forceinline__ void lin_w(int i, int& i0, int& i1, float& w) {
  float f = 0.5f * (float)i - 0.25f;
  f = fminf(fmaxf(f, 0.0f), 6.0f);
  i0 = (int)f;
  w = f - (float)i0;
  i1 = (i0 + 1 < 7) ? i0 + 1 : 6;
}

__device__ __forceinline__ float interp3(const float* __restrict__ p, int x, int y, int z) {
  int x0, x1, y0, y1, z0, z1; float wx, wy, wz;
  lin_w(x, x0, x1, wx); lin_w(y, y0, y1, wy); lin_w(z, z0, z1, wz);
  float c000 = p[x0*49 + y0*7 + z0], c001 = p[x0*49 + y0*7 + z1];
  float c010 = p[x0*49 + y1*7 + z0], c011 = p[x0*49 + y1*7 + z1];
  float c100 = p[x1*49 + y0*7 + z0], c101 = p[x1*49 + y0*7 + z1];
  float c110 = p[x1*49 + y1*7 + z0], c111 = p[x1*49 + y1*7 + z1];
  float c00 = c000 + wz * (c001 - c000), c01 = c010 + wz * (c011 - c010);
  float c10 = c100 + wz * (c101 - c100), c11 = c110 + wz * (c111 - c110);
  float c0 = c00 + wy * (c01 - c00), c1 = c10 + wy * (c11 - c10);
  return c0 + wx * (c1 - c0);
}

// ---------------- bias1[h][a][B1W] = interp(an)[h,a,n] + ah[x]+aw[y]+ad[z] ------
__global__ void bias1_kernel(const float* __restrict__ an, const float* __restrict__ ah,
                             const float* __restrict__ aw, const float* __restrict__ ad,
                             bf16* __restrict__ out) {
  int h = blockIdx.x / ADLA_N, a = blockIdx.x % ADLA_N;
  const float* anp = an + ((size_t)h * ADLA_N + a) * 343;
  const float* ahp = ah + ((size_t)h * ADLA_N + a) * 14;
  const float* awp = aw + ((size_t)h * ADLA_N + a) * 14;
  const float* adp = ad + ((size_t)h * ADLA_N + a) * 14;
  bf16* op = out + ((size_t)h * ADLA_N + a) * B1W;
  for (int n = threadIdx.x; n < B1W; n += 256) {
    if (n < NTOK) {
      int x = n / 196, y = (n / 14) % 14, z = n % 14;
      float v = interp3(anp, x, y, z) + ahp[x] + awp[y] + adp[z];
      op[n] = (bf16)v;
    } else {
      op[n] = (bf16)0.f;   // finite zero pad (read by attn1, masked)
    }
  }
}

// ---------------- bias2[h][n][B2W] = interp(na)[h,a,n] + ha[x,a]+wa[y,a]+da[z,a] -
__global__ void bias2_kernel(const float* __restrict__ na, const float* __restrict__ ha,
                             const float* __restrict__ wa, const float* __restrict__ da,
                             bf16* __restrict__ out) {
  size_t idx = (size_t)blockIdx.x * 256 + threadIdx.x;
  if (idx >= (size_t)8 * NTOK * B2W) return;
  int a = (int)(idx % B2W);
  int n = (int)((idx / B2W) % NTOK);
  int h = (int)(idx / ((size_t)B2W * NTOK));
  if (a >= ADLA_N) { out[idx] = (bf16)0.f; return; }  // finite zero pad
  int x = n / 196, y = (n / 14) % 14, z = n % 14;
  const float* nap = na + ((size_t)h * ADLA_N + a) * 343;
  float v = interp3(nap, x, y, z)
          + ha[((size_t)h * 14 + x) * ADLA_N + a]
          + wa[((size_t)h * 14 + y) * ADLA_N + a]
          + da[((size_t)h * 14 + z) * ADLA_N + a];
  out[idx] = (bf16)v;
}

// ---------------- 128x128 MFMA GEMM, K=384, B^T (bf16) --------------------------
// MODE 0: A=f32 input, split bf16 outputs q/k/v (N=1152)
// MODE 1: A=bf16, +f32 bias, single f32 output (N=384)  <- final projection
template <int MODE, typename AT, typename OT>
__global__ __launch_bounds__(256)
void gemm128(const AT* __restrict__ A, const bf16* __restrict__ BT, int M,
             OT* __restrict__ O0, bf16* __restrict__ O1, bf16* __restrict__ O2,
             const float* __restrict__ bias) {
  __shared__ __align__(16) bf16 As[128 * 32];
  __shared__ __align__(16) bf16 Bs[128 * 32];
  const int tid = threadIdx.x;
  const int wv = tid >> 6, lane = tid & 63;
  const int m0 = blockIdx.x * 128, n0 = blockIdx.y * 128;
  const int wr = wv >> 1, wc = wv & 1;
  f32x4 zero4 = {0.f, 0.f, 0.f, 0.f};
  f32x4 acc[4][4];
#pragma unroll
  for (int i = 0; i < 4; i++)
#pragma unroll
    for (int j = 0; j < 4; j++) acc[i][j] = zero4;

  for (int k0 = 0; k0 < 384; k0 += 32) {
    __syncthreads();
#pragma unroll
    for (int i = 0; i < 2; i++) {
      int flat = i * 256 + tid;
      int row = flat >> 2, cg = flat & 3;
      int gr = m0 + row; if (gr >= M) gr = M - 1;
      bf16x8 av;
      if constexpr (sizeof(AT) == 4) {
        const float4* s4 = (const float4*)(A + (size_t)gr * 384 + k0 + cg * 8);
        float4 a = s4[0], b = s4[1];
        av[0]=(bf16)a.x; av[1]=(bf16)a.y; av[2]=(bf16)a.z; av[3]=(bf16)a.w;
        av[4]=(bf16)b.x; av[5]=(bf16)b.y; av[6]=(bf16)b.z; av[7]=(bf16)b.w;
      } else {
        av = *(const bf16x8*)(A + (size_t)gr * 384 + k0 + cg * 8);
      }
      *(bf16x8*)(As + flat * 8) = av;
      int nr = n0 + row;
      *(bf16x8*)(Bs + flat * 8) = *(const bf16x8*)(BT + (size_t)nr * 384 + k0 + cg * 8);
    }
    __syncthreads();
    bf16x8 af[4], bfr[4];
#pragma unroll
    for (int t = 0; t < 4; t++) {
      af[t]  = *(const bf16x8*)(As + (wr * 64 + t * 16 + (lane & 15)) * 32 + (lane >> 4) * 8);
      bfr[t] = *(const bf16x8*)(Bs + (wc * 64 + t * 16 + (lane & 15)) * 32 + (lane >> 4) * 8);
    }
#pragma unroll
    for (int rt = 0; rt < 4; rt++)
#pragma unroll
      for (int ct = 0; ct < 4; ct++)
        acc[rt][ct] = __builtin_amdgcn_mfma_f32_16x16x32_bf16(af[rt], bfr[ct], acc[rt][ct], 0, 0, 0);
  }
  const int quad = lane >> 4, colL = lane & 15;
#pragma unroll
  for (int rt = 0; rt < 4; rt++) {
#pragma unroll
    for (int ct = 0; ct < 4; ct++) {
      int gcol = n0 + wc * 64 + ct * 16 + colL;
#pragma unroll
      for (int r = 0; r < 4; r++) {
        int grow = m0 + wr * 64 + rt * 16 + quad * 4 + r;
        if (grow < M) {
          float v = acc[rt][ct][r];
          if (MODE == 1) {
            v += bias[gcol];
            O0[(size_t)grow * 384 + gcol] = (OT)v;   // OT=float for final output
          } else {
            bf16* dst; int c;
            if (gcol < 384)      { dst = (bf16*)O0; c = gcol; }
            else if (gcol < 768) { dst = O1; c = gcol - 384; }
            else                 { dst = O2; c = gcol - 768; }
            dst[(size_t)grow * 384 + c] = (bf16)v;
          }
        }
      }
    }
  }
}

// ---------------- v -> vT  ([b][n][c] -> [b][c][n]) -----------------------------
__global__ void transpose_v(const bf16* __restrict__ v, bf16* __restrict__ vT) {
  __shared__ bf16 t[64][65];
  int n0 = blockIdx.x * 64, c0 = blockIdx.y * 64, b = blockIdx.z;
  int tid = threadIdx.x;
  int cl = tid & 63, rs = tid >> 6;
  for (int j = 0; j < 16; j++) {
    int r = rs * 16 + j;
    int n = n0 + r;
    if (n < NTOK) t[cl][r] = v[((size_t)b * NTOK + n) * DIM + c0 + cl];
  }
  __syncthreads();
  int nl = tid & 63, cs = tid >> 6;
  int n = n0 + nl;
  if (n < NTOK)
    for (int j = 0; j < 16; j++) {
      int cc = cs * 16 + j;
      vT[((size_t)b * DIM + c0 + cc) * NTOK + n] = t[cc][nl];
    }
}

// ---------------- 2x2x2 mean-pool of q -> adla [b][343][384] --------------------
__global__ void pool_kernel(const bf16* __restrict__ q, bf16* __restrict__ adla) {
  int idx = blockIdx.x * 256 + threadIdx.x;
  if (idx >= BATCH * ADLA_N * DIM) return;
  int c = idx % DIM;
  int a = (idx / DIM) % ADLA_N;
  int b = idx / (DIM * ADLA_N);
  int a0 = a / 49, a1 = (a / 7) % 7, a2 = a % 7;
  float s = 0.f;
#pragma unroll
  for (int i = 0; i < 2; i++)
#pragma unroll
    for (int j = 0; j < 2; j++)
#pragma unroll
      for (int k = 0; k < 2; k++) {
        int n = (a0 * 2 + i) * 196 + (a1 * 2 + j) * 14 + (a2 * 2 + k);
        s += (float)q[((size_t)b * NTOK + n) * DIM + c];
      }
  adla[idx] = (bf16)(s * 0.125f);
}

// ---------------- unified no-max streaming attention (bf16 internals) -----------
// Rows R (64-tile) over A; softmax over columns C in chunks of 128.
// S = (A @ K^T)*SCALE + Bias ; P = exp(S) (masked); O = P @ V^T ; O /= rowsum.
// mode 0 (attn1): store O transposed -> advT[(b*8+h)*48 + d][ADV_W] at col a
// mode 1 (attn2): store O row-major  -> out[(b*AR + n)*384 + h*48 + d]
__global__ __launch_bounds__(256)
void attn_kernel(const bf16* __restrict__ Amat, const bf16* __restrict__ Kmat,
                 const bf16* __restrict__ Vt, const bf16* __restrict__ Bias,
                 bf16* __restrict__ Out,
                 int AR, int NC, int biasW,
                 size_t vtB, size_t vtH, int vtS, int mode) {
  __shared__ __align__(16) bf16 aT[64 * 64];
  __shared__ __align__(16) bf16 kT[128 * 64];
  __shared__ __align__(16) bf16 vTs[48 * 128];
  __shared__ __align__(16) bf16 pT[64 * 128];
  const int tid = threadIdx.x;
  const int wv = tid >> 6, lane = tid & 63;
  const int bI = blockIdx.y >> 3, h = blockIdx.y & 7;
  const int r0 = blockIdx.x * 64;
  const int quad = lane >> 4, colL = lane & 15;

  // A tile [64][64], zero-padded in k (cols 48..63), rows clamped
#pragma unroll
  for (int i = 0; i < 2; i++) {
    int flat = i * 256 + tid;
    int row = flat >> 3, cg = flat & 7;
    int r = r0 + row; if (r >= AR) r = AR - 1;
    bf16x8 val;
#pragma unroll
    for (int e = 0; e < 8; e++) val[e] = (bf16)0.f;
    if (cg < 6) val = *(const bf16x8*)(Amat + ((size_t)bI * AR + r) * DIM + h * HEAD_DIM + cg * 8);
    *(bf16x8*)(aT + flat * 8) = val;
  }

  f32x4 zero4 = {0.f, 0.f, 0.f, 0.f};
  f32x4 acc[3] = {zero4, zero4, zero4};
  float rowsum[4] = {0.f, 0.f, 0.f, 0.f};
  const int nChunks = (NC + 127) >> 7;

  for (int ch = 0; ch < nChunks; ch++) {
    const int c0 = ch << 7;
    __syncthreads();
    // K tile [128][64]; k-cols 48..63 hold finite in-bounds copies (A zero there)
#pragma unroll
    for (int i = 0; i < 4; i++) {
      int flat = i * 256 + tid;
      int row = flat >> 3, cg = flat & 7;
      int kg = (cg < 6) ? cg : 0;
      int gr = c0 + row; if (gr >= NC) gr = NC - 1;
      *(bf16x8*)(kT + flat * 8) =
          *(const bf16x8*)(Kmat + ((size_t)bI * NC + gr) * DIM + h * HEAD_DIM + kg * 8);
    }
    // V^T tile [48][128]; clamp column so reads stay inside the written row
#pragma unroll
    for (int i = 0; i < 3; i++) {
      int flat = i * 256 + tid;
      int d = flat >> 4, cg = flat & 15;
      int cc = c0 + cg * 8; if (cc > vtS - 8) cc = vtS - 8;
      *(bf16x8*)(vTs + flat * 8) =
          *(const bf16x8*)(Vt + (size_t)bI * vtB + (size_t)h * vtH + (size_t)d * vtS + cc);
    }
    // Bias tile -> pT [64][128]
#pragma unroll
    for (int i = 0; i < 4; i++) {
      int flat = i * 256 + tid;
      int row = flat >> 4, cg = flat & 15;
      int r = r0 + row; if (r >= AR) r = AR - 1;
      *(bf16x8*)(pT + flat * 8) =
          *(const bf16x8*)(Bias + ((size_t)h * AR + r) * biasW + c0 + cg * 8);
    }
    __syncthreads();

    // S phase
    bf16x8 af0 = *(const bf16x8*)(aT + (wv * 16 + colL) * 64 + quad * 8);
    bf16x8 af1 = *(const bf16x8*)(aT + (wv * 16 + colL) * 64 + 32 + quad * 8);
    f32x4 sacc[8];
#pragma unroll
    for (int ct = 0; ct < 8; ct++) sacc[ct] = zero4;
#pragma unroll
    for (int ct = 0; ct < 8; ct++) {
      bf16x8 b0 = *(const bf16x8*)(kT + (ct * 16 + colL) * 64 + quad * 8);
      bf16x8 b1 = *(const bf16x8*)(kT + (ct * 16 + colL) * 64 + 32 + quad * 8);
      sacc[ct] = __builtin_amdgcn_mfma_f32_16x16x32_bf16(af0, b0, sacc[ct], 0, 0, 0);
      sacc[ct] = __builtin_amdgcn_mfma_f32_16x16x32_bf16(af1, b1, sacc[ct], 0, 0, 0);
    }
    // bias + exp -> P back into pT
#pragma unroll
    for (int ct = 0; ct < 8; ct++) {
      int c = ct * 16 + colL;
      bool valid = (c0 + c) < NC;
#pragma unroll
      for (int r = 0; r < 4; r++) {
        int row = wv * 16 + quad * 4 + r;
        float s = sacc[ct][r] * SCALE + (float)pT[row * 128 + c];
        s = fminf(fmaxf(s, -60.f), 60.f);
        float p = valid ? __expf(s) : 0.f;
        rowsum[r] += p;
        pT[row * 128 + c] = (bf16)p;
      }
    }
    // PV phase: acc += P @ V^T (K = 128)
#pragma unroll
    for (int ks = 0; ks < 4; ks++) {
      bf16x8 pf = *(const bf16x8*)(pT + (wv * 16 + colL) * 128 + ks * 32 + quad * 8);
#pragma unroll
      for (int dt = 0; dt < 3; dt++) {
        bf16x8 vf = *(const bf16x8*)(vTs + (dt * 16 + colL) * 128 + ks * 32 + quad * 8);
        acc[dt] = __builtin_amdgcn_mfma_f32_16x16x32_bf16(pf, vf, acc[dt], 0, 0, 0);
      }
    }
  }

  // rowsum reduce over the 16 col-lanes within each quad
#pragma unroll
  for (int m = 1; m < 16; m <<= 1)
#pragma unroll
    for (int r = 0; r < 4; r++) rowsum[r] += __shfl_xor(rowsum[r], m, 64);
  float inv[4];
#pragma unroll
  for (int r = 0; r < 4; r++) inv[r] = 1.f / rowsum[r];

  if (mode == 0) {
#pragma unroll
    for (int dt = 0; dt < 3; dt++)
#pragma unroll
      for (int r = 0; r < 4; r++) {
        int a = r0 + wv * 16 + quad * 4 + r;
        size_t rowD = (size_t)(bI * 8 + h) * 48 + dt * 16 + colL;
        if (a < AR)
          Out[rowD * ADV_W + a] = (bf16)(acc[dt][r] * inv[r]);
        else if (a < ADV_W)
          Out[rowD * ADV_W + a] = (bf16)0.f;
      }
  } else {
#pragma unroll
    for (int dt = 0; dt < 3; dt++)
#pragma unroll
      for (int r = 0; r < 4; r++) {
        int n = r0 + wv * 16 + quad * 4 + r;
        if (n < AR)
          Out[((size_t)bI * AR + n) * DIM + h * HEAD_DIM + dt * 16 + colL] = (bf16)(acc[dt][r] * inv[r]);
      }
  }
}

// ---------------- depthwise 3x3x3 conv on vT, RMW-add into io [b][n][c] ---------
__global__ void dwc_kernel(const bf16* __restrict__ vT, const float* __restrict__ w,
                           const float* __restrict__ bias, bf16* __restrict__ io) {
  __shared__ float tile[64][65];
  int n0 = blockIdx.x * 64, c0 = blockIdx.y * 64, b = blockIdx.z;
  int tid = threadIdx.x;
  int nl = tid & 63, csub = tid >> 6;
  int n = n0 + nl;
  if (n < NTOK) {
    int x = n / 196, y = (n / 14) % 14, z = n % 14;
    for (int j = 0; j < 16; j++) {
      int cl = csub * 16 + j;
      int c = c0 + cl;
      const bf16* base = vT + ((size_t)b * DIM + c) * NTOK;
      const float* wc = w + c * 27;
      float s = bias[c];
      for (int dx = -1; dx <= 1; dx++) {
        int X = x + dx; if (X < 0 || X >= 14) continue;
        for (int dy = -1; dy <= 1; dy++) {
          int Y = y + dy; if (Y < 0 || Y >= 14) continue;
          for (int dz = -1; dz <= 1; dz++) {
            int Z = z + dz; if (Z < 0 || Z >= 14) continue;
            s += (float)base[X * 196 + Y * 14 + Z] * wc[(dx + 1) * 9 + (dy + 1) * 3 + (dz + 1)];
          }
        }
      }
      tile[cl][nl] = s;
    }
  }
  __syncthreads();
  int cl2 = tid & 63, nsub = tid >> 6;
  for (int j = 0; j < 16; j++) {
    int nl2 = nsub * 16 + j;
    int n2 = n0 + nl2;
    if (n2 < NTOK) {
      size_t idx = ((size_t)b * NTOK + n2) * DIM + c0 + cl2;
      io[idx] = (bf16)((float)io[idx] + tile[cl2][nl2]);
    }
  }
}

// -------------------------------------------------------------------------------
extern "C" void kernel_launch(void* const* d_in, const int* in_sizes, int n_in,
                              void* d_out, int out_size, void* d_ws, size_t ws_size,
                              hipStream_t stream) {
  // Inputs f32 (verified by on-device probe in R5); output f32 (reference dtype).
  const float* x     = (const float*)d_in[0];
  const float* Wq    = (const float*)d_in[1];
  const float* Wkv   = (const float*)d_in[2];
  const float* Wproj = (const float*)d_in[3];
  const float* bproj = (const float*)d_in[4];
  const float* dwcw  = (const float*)d_in[5];
  const float* dwcb  = (const float*)d_in[6];
  const float* an    = (const float*)d_in[7];
  const float* na    = (const float*)d_in[8];
  const float* ahb   = (const float*)d_in[9];
  const float* awb   = (const float*)d_in[10];
  const float* adb   = (const float*)d_in[11];
  const float* hab   = (const float*)d_in[12];
  const float* wab   = (const float*)d_in[13];
  const float* dab   = (const float*)d_in[14];
  float* out = (float*)d_out;

  uint8_t* ws = (uint8_t*)d_ws;
  size_t off = 0;
  auto carve = [&](size_t elems) -> bf16* {
    bf16* p = (bf16*)(ws + off);
    off += ((elems * 2 + 255) & ~(size_t)255);
    return p;
  };
  bf16* wtall  = carve((size_t)1152 * 384);
  bf16* wprojT = carve((size_t)384 * 384);
  bf16* qb     = carve((size_t)MTOT * 384 + 128);
  bf16* kb     = carve((size_t)MTOT * 384 + 128);   // bias2 aliases after attn1
  bf16* vb     = carve((size_t)MTOT * 384 + 128);   // aout aliases after transpose_v
  bf16* vTb    = carve((size_t)MTOT * 384 + 128);
  bf16* adla   = carve((size_t)BATCH * ADLA_N * 384 + 128);
  bf16* advT   = carve((size_t)64 * 48 * ADV_W + 128);
  bf16* bias1  = carve((size_t)8 * ADLA_N * B1W);
  bf16* bias2  = kb;   // kb dead after attn1
  bf16* aout   = vb;   // vb dead after transpose_v

  transpose_weights<<<dim3((1152 * 384 + 384 * 384 + 255) / 256), 256, 0, stream>>>(
      Wq, Wkv, Wproj, wtall, wprojT);
  bias1_kernel<<<dim3(8 * ADLA_N), 256, 0, stream>>>(an, ahb, awb, adb, bias1);
  gemm128<0, float, bf16><<<dim3(172, 9), 256, 0, stream>>>(
      x, wtall, MTOT, qb, kb, vb, nullptr);
  transpose_v<<<dim3(43, 6, 8), 256, 0, stream>>>(vb, vTb);
  pool_kernel<<<dim3((BATCH * ADLA_N * DIM + 255) / 256), 256, 0, stream>>>(qb, adla);
  attn_kernel<<<dim3(6, 64), 256, 0, stream>>>(
      adla, kb, vTb, bias1, advT,
      ADLA_N, NTOK, B1W, (size_t)384 * NTOK, (size_t)48 * NTOK, NTOK, 0);
  bias2_kernel<<<dim3((int)(((size_t)8 * NTOK * B2W + 255) / 256)), 256, 0, stream>>>(
      na, hab, wab, dab, bias2);
  attn_kernel<<<dim3(43, 64), 256, 0, stream>>>(
      qb, adla, advT, bias2, aout,
      NTOK, ADLA_N, B2W, (size_t)8 * 48 * ADV_W, (size_t)48 * ADV_W, ADV_W, 1);
  dwc_kernel<<<dim3(43, 6, 8), 256, 0, stream>>>(vTb, dwcw, dwcb, aout);
  gemm128<1, bf16, float><<<dim3(172, 3), 256, 0, stream>>>(
      aout, wprojT, MTOT, out, nullptr, nullptr, bproj);
}

// Round 7
// 743.457 us; speedup vs baseline: 1.0602x; 1.0602x over previous
//
#include <hip/hip_runtime.h>
#include <hip/hip_bf16.h>
#include <cstdint>

typedef __bf16 bf16;
typedef __attribute__((ext_vector_type(8))) __bf16 bf16x8;
typedef __attribute__((ext_vector_type(4))) float f32x4;

constexpr int DIM = 384;
constexpr int HEAD_DIM = 48;
constexpr int ADLA_N = 343;
constexpr int NTOK = 2744;        // 14^3
constexpr int BATCH = 8;
constexpr int MTOT = BATCH * NTOK; // 21952
constexpr float SCALE = 0.14433756729740643f; // 48^-0.5
constexpr int B1W = 2816;          // bias1 padded width (22*128)
constexpr int B2W = 384;           // bias2 padded width (3*128)
constexpr int ADV_W = 352;         // adla_v^T padded cols

// ---------------- weight transpose (f32 in -> bf16 out) -------------------------
__global__ void transpose_weights(const float* __restrict__ Wq,
                                  const float* __restrict__ Wkv,
                                  const float* __restrict__ Wproj,
                                  bf16* __restrict__ WTall,
                                  bf16* __restrict__ WprojT) {
  int idx = blockIdx.x * 256 + threadIdx.x;
  const int total1 = 1152 * 384;
  if (idx < total1) {
    int j = idx / 384, k = idx % 384;
    WTall[idx] = (bf16)((j < 384) ? Wq[k * 384 + j] : Wkv[k * 768 + (j - 384)]);
  } else {
    int i2 = idx - total1;
    if (i2 < 384 * 384) {
      int j = i2 / 384, k = i2 % 384;
      WprojT[i2] = (bf16)Wproj[k * 384 + j];
    }
  }
}

// ---------------- trilinear interp helpers (out 14 from in 7) ------------------
__device__ __forceinline__ void lin_w(int i, int& i0, int& i1, float& w) {
  float f = 0.5f * (float)i - 0.25f;
  f = fminf(fmaxf(f, 0.0f), 6.0f);
  i0 = (int)f;
  w = f - (float)i0;
  i1 = (i0 + 1 < 7) ? i0 + 1 : 6;
}

__device__ __forceinline__ float interp3(const float* __restrict__ p, int x, int y, int z) {
  int x0, x1, y0, y1, z0, z1; float wx, wy, wz;
  lin_w(x, x0, x1, wx); lin_w(y, y0, y1, wy); lin_w(z, z0, z1, wz);
  float c000 = p[x0*49 + y0*7 + z0], c001 = p[x0*49 + y0*7 + z1];
  float c010 = p[x0*49 + y1*7 + z0], c011 = p[x0*49 + y1*7 + z1];
  float c100 = p[x1*49 + y0*7 + z0], c101 = p[x1*49 + y0*7 + z1];
  float c110 = p[x1*49 + y1*7 + z0], c111 = p[x1*49 + y1*7 + z1];
  float c00 = c000 + wz * (c001 - c000), c01 = c010 + wz * (c011 - c010);
  float c10 = c100 + wz * (c101 - c100), c11 = c110 + wz * (c111 - c110);
  float c0 = c00 + wy * (c01 - c00), c1 = c10 + wy * (c11 - c10);
  return c0 + wx * (c1 - c0);
}

// ---------------- bias1[h][a][B1W] = interp(an)[h,a,n] + ah[x]+aw[y]+ad[z] ------
__global__ void bias1_kernel(const float* __restrict__ an, const float* __restrict__ ah,
                             const float* __restrict__ aw, const float* __restrict__ ad,
                             bf16* __restrict__ out) {
  int h = blockIdx.x / ADLA_N, a = blockIdx.x % ADLA_N;
  const float* anp = an + ((size_t)h * ADLA_N + a) * 343;
  const float* ahp = ah + ((size_t)h * ADLA_N + a) * 14;
  const float* awp = aw + ((size_t)h * ADLA_N + a) * 14;
  const float* adp = ad + ((size_t)h * ADLA_N + a) * 14;
  bf16* op = out + ((size_t)h * ADLA_N + a) * B1W;
  for (int n = threadIdx.x; n < B1W; n += 256) {
    if (n < NTOK) {
      int x = n / 196, y = (n / 14) % 14, z = n % 14;
      float v = interp3(anp, x, y, z) + ahp[x] + awp[y] + adp[z];
      op[n] = (bf16)v;
    } else {
      op[n] = (bf16)0.f;   // finite zero pad (read by attn1, masked)
    }
  }
}

// ---------------- bias2[h][n][B2W] = interp(na)[h,a,n] + ha[x,a]+wa[y,a]+da[z,a] -
__global__ void bias2_kernel(const float* __restrict__ na, const float* __restrict__ ha,
                             const float* __restrict__ wa, const float* __restrict__ da,
                             bf16* __restrict__ out) {
  size_t idx = (size_t)blockIdx.x * 256 + threadIdx.x;
  if (idx >= (size_t)8 * NTOK * B2W) return;
  int a = (int)(idx % B2W);
  int n = (int)((idx / B2W) % NTOK);
  int h = (int)(idx / ((size_t)B2W * NTOK));
  if (a >= ADLA_N) { out[idx] = (bf16)0.f; return; }  // finite zero pad
  int x = n / 196, y = (n / 14) % 14, z = n % 14;
  const float* nap = na + ((size_t)h * ADLA_N + a) * 343;
  float v = interp3(nap, x, y, z)
          + ha[((size_t)h * 14 + x) * ADLA_N + a]
          + wa[((size_t)h * 14 + y) * ADLA_N + a]
          + da[((size_t)h * 14 + z) * ADLA_N + a];
  out[idx] = (bf16)v;
}

// ---------------- 128x128 MFMA GEMM, K=384, B^T (bf16) --------------------------
// MODE 0: A=f32 input, split bf16 outputs q/k/v (N=1152)
// MODE 1: A=bf16, +f32 bias, single f32 output (N=384)  <- final projection
template <int MODE, typename AT, typename OT>
__global__ __launch_bounds__(256)
void gemm128(const AT* __restrict__ A, const bf16* __restrict__ BT, int M,
             OT* __restrict__ O0, bf16* __restrict__ O1, bf16* __restrict__ O2,
             const float* __restrict__ bias) {
  __shared__ __align__(16) bf16 As[128 * 32];
  __shared__ __align__(16) bf16 Bs[128 * 32];
  const int tid = threadIdx.x;
  const int wv = tid >> 6, lane = tid & 63;
  const int m0 = blockIdx.x * 128, n0 = blockIdx.y * 128;
  const int wr = wv >> 1, wc = wv & 1;
  f32x4 zero4 = {0.f, 0.f, 0.f, 0.f};
  f32x4 acc[4][4];
#pragma unroll
  for (int i = 0; i < 4; i++)
#pragma unroll
    for (int j = 0; j < 4; j++) acc[i][j] = zero4;

  for (int k0 = 0; k0 < 384; k0 += 32) {
    __syncthreads();
#pragma unroll
    for (int i = 0; i < 2; i++) {
      int flat = i * 256 + tid;
      int row = flat >> 2, cg = flat & 3;
      int gr = m0 + row; if (gr >= M) gr = M - 1;
      bf16x8 av;
      if constexpr (sizeof(AT) == 4) {
        const float4* s4 = (const float4*)(A + (size_t)gr * 384 + k0 + cg * 8);
        float4 a = s4[0], b = s4[1];
        av[0]=(bf16)a.x; av[1]=(bf16)a.y; av[2]=(bf16)a.z; av[3]=(bf16)a.w;
        av[4]=(bf16)b.x; av[5]=(bf16)b.y; av[6]=(bf16)b.z; av[7]=(bf16)b.w;
      } else {
        av = *(const bf16x8*)(A + (size_t)gr * 384 + k0 + cg * 8);
      }
      *(bf16x8*)(As + flat * 8) = av;
      int nr = n0 + row;
      *(bf16x8*)(Bs + flat * 8) = *(const bf16x8*)(BT + (size_t)nr * 384 + k0 + cg * 8);
    }
    __syncthreads();
    bf16x8 af[4], bfr[4];
#pragma unroll
    for (int t = 0; t < 4; t++) {
      af[t]  = *(const bf16x8*)(As + (wr * 64 + t * 16 + (lane & 15)) * 32 + (lane >> 4) * 8);
      bfr[t] = *(const bf16x8*)(Bs + (wc * 64 + t * 16 + (lane & 15)) * 32 + (lane >> 4) * 8);
    }
#pragma unroll
    for (int rt = 0; rt < 4; rt++)
#pragma unroll
      for (int ct = 0; ct < 4; ct++)
        acc[rt][ct] = __builtin_amdgcn_mfma_f32_16x16x32_bf16(af[rt], bfr[ct], acc[rt][ct], 0, 0, 0);
  }
  const int quad = lane >> 4, colL = lane & 15;
#pragma unroll
  for (int rt = 0; rt < 4; rt++) {
#pragma unroll
    for (int ct = 0; ct < 4; ct++) {
      int gcol = n0 + wc * 64 + ct * 16 + colL;
#pragma unroll
      for (int r = 0; r < 4; r++) {
        int grow = m0 + wr * 64 + rt * 16 + quad * 4 + r;
        if (grow < M) {
          float v = acc[rt][ct][r];
          if (MODE == 1) {
            v += bias[gcol];
            O0[(size_t)grow * 384 + gcol] = (OT)v;   // OT=float for final output
          } else {
            bf16* dst; int c;
            if (gcol < 384)      { dst = (bf16*)O0; c = gcol; }
            else if (gcol < 768) { dst = O1; c = gcol - 384; }
            else                 { dst = O2; c = gcol - 768; }
            dst[(size_t)grow * 384 + c] = (bf16)v;
          }
        }
      }
    }
  }
}

// ---------------- v -> vT  ([b][n][c] -> [b][c][n]) -----------------------------
__global__ void transpose_v(const bf16* __restrict__ v, bf16* __restrict__ vT) {
  __shared__ bf16 t[64][65];
  int n0 = blockIdx.x * 64, c0 = blockIdx.y * 64, b = blockIdx.z;
  int tid = threadIdx.x;
  int cl = tid & 63, rs = tid >> 6;
  for (int j = 0; j < 16; j++) {
    int r = rs * 16 + j;
    int n = n0 + r;
    if (n < NTOK) t[cl][r] = v[((size_t)b * NTOK + n) * DIM + c0 + cl];
  }
  __syncthreads();
  int nl = tid & 63, cs = tid >> 6;
  int n = n0 + nl;
  if (n < NTOK)
    for (int j = 0; j < 16; j++) {
      int cc = cs * 16 + j;
      vT[((size_t)b * DIM + c0 + cc) * NTOK + n] = t[cc][nl];
    }
}

// ---------------- 2x2x2 mean-pool of q -> adla [b][343][384] --------------------
__global__ void pool_kernel(const bf16* __restrict__ q, bf16* __restrict__ adla) {
  int idx = blockIdx.x * 256 + threadIdx.x;
  if (idx >= BATCH * ADLA_N * DIM) return;
  int c = idx % DIM;
  int a = (idx / DIM) % ADLA_N;
  int b = idx / (DIM * ADLA_N);
  int a0 = a / 49, a1 = (a / 7) % 7, a2 = a % 7;
  float s = 0.f;
#pragma unroll
  for (int i = 0; i < 2; i++)
#pragma unroll
    for (int j = 0; j < 2; j++)
#pragma unroll
      for (int k = 0; k < 2; k++) {
        int n = (a0 * 2 + i) * 196 + (a1 * 2 + j) * 14 + (a2 * 2 + k);
        s += (float)q[((size_t)b * NTOK + n) * DIM + c];
      }
  adla[idx] = (bf16)(s * 0.125f);
}

// ---------------- unified no-max streaming attention (bf16 internals) -----------
__global__ __launch_bounds__(256)
void attn_kernel(const bf16* __restrict__ Amat, const bf16* __restrict__ Kmat,
                 const bf16* __restrict__ Vt, const bf16* __restrict__ Bias,
                 bf16* __restrict__ Out,
                 int AR, int NC, int biasW,
                 size_t vtB, size_t vtH, int vtS, int mode) {
  __shared__ __align__(16) bf16 aT[64 * 64];
  __shared__ __align__(16) bf16 kT[128 * 64];
  __shared__ __align__(16) bf16 vTs[48 * 128];
  __shared__ __align__(16) bf16 pT[64 * 128];
  const int tid = threadIdx.x;
  const int wv = tid >> 6, lane = tid & 63;
  const int bI = blockIdx.y >> 3, h = blockIdx.y & 7;
  const int r0 = blockIdx.x * 64;
  const int quad = lane >> 4, colL = lane & 15;

  // A tile [64][64], zero-padded in k (cols 48..63), rows clamped
#pragma unroll
  for (int i = 0; i < 2; i++) {
    int flat = i * 256 + tid;
    int row = flat >> 3, cg = flat & 7;
    int r = r0 + row; if (r >= AR) r = AR - 1;
    bf16x8 val;
#pragma unroll
    for (int e = 0; e < 8; e++) val[e] = (bf16)0.f;
    if (cg < 6) val = *(const bf16x8*)(Amat + ((size_t)bI * AR + r) * DIM + h * HEAD_DIM + cg * 8);
    *(bf16x8*)(aT + flat * 8) = val;
  }

  f32x4 zero4 = {0.f, 0.f, 0.f, 0.f};
  f32x4 acc[3] = {zero4, zero4, zero4};
  float rowsum[4] = {0.f, 0.f, 0.f, 0.f};
  const int nChunks = (NC + 127) >> 7;

  for (int ch = 0; ch < nChunks; ch++) {
    const int c0 = ch << 7;
    __syncthreads();
    // K tile [128][64]; k-cols 48..63 hold finite in-bounds copies (A zero there)
#pragma unroll
    for (int i = 0; i < 4; i++) {
      int flat = i * 256 + tid;
      int row = flat >> 3, cg = flat & 7;
      int kg = (cg < 6) ? cg : 0;
      int gr = c0 + row; if (gr >= NC) gr = NC - 1;
      *(bf16x8*)(kT + flat * 8) =
          *(const bf16x8*)(Kmat + ((size_t)bI * NC + gr) * DIM + h * HEAD_DIM + kg * 8);
    }
    // V^T tile [48][128]; clamp column so reads stay inside the written row
#pragma unroll
    for (int i = 0; i < 3; i++) {
      int flat = i * 256 + tid;
      int d = flat >> 4, cg = flat & 15;
      int cc = c0 + cg * 8; if (cc > vtS - 8) cc = vtS - 8;
      *(bf16x8*)(vTs + flat * 8) =
          *(const bf16x8*)(Vt + (size_t)bI * vtB + (size_t)h * vtH + (size_t)d * vtS + cc);
    }
    // Bias tile -> pT [64][128]
#pragma unroll
    for (int i = 0; i < 4; i++) {
      int flat = i * 256 + tid;
      int row = flat >> 4, cg = flat & 15;
      int r = r0 + row; if (r >= AR) r = AR - 1;
      *(bf16x8*)(pT + flat * 8) =
          *(const bf16x8*)(Bias + ((size_t)h * AR + r) * biasW + c0 + cg * 8);
    }
    __syncthreads();

    // S phase
    bf16x8 af0 = *(const bf16x8*)(aT + (wv * 16 + colL) * 64 + quad * 8);
    bf16x8 af1 = *(const bf16x8*)(aT + (wv * 16 + colL) * 64 + 32 + quad * 8);
    f32x4 sacc[8];
#pragma unroll
    for (int ct = 0; ct < 8; ct++) sacc[ct] = zero4;
#pragma unroll
    for (int ct = 0; ct < 8; ct++) {
      bf16x8 b0 = *(const bf16x8*)(kT + (ct * 16 + colL) * 64 + quad * 8);
      bf16x8 b1 = *(const bf16x8*)(kT + (ct * 16 + colL) * 64 + 32 + quad * 8);
      sacc[ct] = __builtin_amdgcn_mfma_f32_16x16x32_bf16(af0, b0, sacc[ct], 0, 0, 0);
      sacc[ct] = __builtin_amdgcn_mfma_f32_16x16x32_bf16(af1, b1, sacc[ct], 0, 0, 0);
    }
    // bias + exp -> P back into pT
#pragma unroll
    for (int ct = 0; ct < 8; ct++) {
      int c = ct * 16 + colL;
      bool valid = (c0 + c) < NC;
#pragma unroll
      for (int r = 0; r < 4; r++) {
        int row = wv * 16 + quad * 4 + r;
        float s = sacc[ct][r] * SCALE + (float)pT[row * 128 + c];
        s = fminf(fmaxf(s, -60.f), 60.f);
        float p = valid ? __expf(s) : 0.f;
        rowsum[r] += p;
        pT[row * 128 + c] = (bf16)p;
      }
    }
    // PV phase: acc += P @ V^T (K = 128)
#pragma unroll
    for (int ks = 0; ks < 4; ks++) {
      bf16x8 pf = *(const bf16x8*)(pT + (wv * 16 + colL) * 128 + ks * 32 + quad * 8);
#pragma unroll
      for (int dt = 0; dt < 3; dt++) {
        bf16x8 vf = *(const bf16x8*)(vTs + (dt * 16 + colL) * 128 + ks * 32 + quad * 8);
        acc[dt] = __builtin_amdgcn_mfma_f32_16x16x32_bf16(pf, vf, acc[dt], 0, 0, 0);
      }
    }
  }

  // rowsum reduce over the 16 col-lanes within each quad
#pragma unroll
  for (int m = 1; m < 16; m <<= 1)
#pragma unroll
    for (int r = 0; r < 4; r++) rowsum[r] += __shfl_xor(rowsum[r], m, 64);
  float inv[4];
#pragma unroll
  for (int r = 0; r < 4; r++) inv[r] = 1.f / rowsum[r];

  if (mode == 0) {
#pragma unroll
    for (int dt = 0; dt < 3; dt++)
#pragma unroll
      for (int r = 0; r < 4; r++) {
        int a = r0 + wv * 16 + quad * 4 + r;
        size_t rowD = (size_t)(bI * 8 + h) * 48 + dt * 16 + colL;
        if (a < AR)
          Out[rowD * ADV_W + a] = (bf16)(acc[dt][r] * inv[r]);
        else if (a < ADV_W)
          Out[rowD * ADV_W + a] = (bf16)0.f;
      }
  } else {
#pragma unroll
    for (int dt = 0; dt < 3; dt++)
#pragma unroll
      for (int r = 0; r < 4; r++) {
        int n = r0 + wv * 16 + quad * 4 + r;
        if (n < AR)
          Out[((size_t)bI * AR + n) * DIM + h * HEAD_DIM + dt * 16 + colL] = (bf16)(acc[dt][r] * inv[r]);
      }
  }
}

// ---------------- depthwise 3x3x3 conv, lane=channel, RMW-add into io -----------
// v is [b][n][c] (NOT transposed): for fixed n, 64 lanes read 64 consecutive
// channels -> coalesced; boundary masks depend only on n -> wave-uniform.
__global__ __launch_bounds__(256)
void dwc_kernel(const bf16* __restrict__ v, const float* __restrict__ w,
                const float* __restrict__ bias, bf16* __restrict__ io) {
  const int tid = threadIdx.x;
  const int lane = tid & 63, wv = tid >> 6;
  const int c = blockIdx.y * 64 + lane;
  const int b = blockIdx.z;
  const int n_base = blockIdx.x * 32 + wv * 8;
  float wt[27];
#pragma unroll
  for (int t = 0; t < 27; t++) wt[t] = w[c * 27 + t];
  const float bs = bias[c];
  const bf16* vb_ = v + (size_t)b * NTOK * DIM;
  bf16* iob = io + (size_t)b * NTOK * DIM;
#pragma unroll
  for (int k = 0; k < 8; k++) {
    int n = n_base + k;
    if (n >= NTOK) break;
    int x = n / 196, y = (n / 14) % 14, z = n % 14;
    float s = bs;
#pragma unroll
    for (int dx = -1; dx <= 1; dx++) {
      int X = x + dx; if ((unsigned)X >= 14u) continue;   // wave-uniform
#pragma unroll
      for (int dy = -1; dy <= 1; dy++) {
        int Y = y + dy; if ((unsigned)Y >= 14u) continue; // wave-uniform
#pragma unroll
        for (int dz = -1; dz <= 1; dz++) {
          int Z = z + dz; if ((unsigned)Z >= 14u) continue; // wave-uniform
          s += (float)vb_[(size_t)(X * 196 + Y * 14 + Z) * DIM + c]
             * wt[(dx + 1) * 9 + (dy + 1) * 3 + (dz + 1)];
        }
      }
    }
    size_t idx = (size_t)n * DIM + c;
    iob[idx] = (bf16)((float)iob[idx] + s);
  }
}

// -------------------------------------------------------------------------------
extern "C" void kernel_launch(void* const* d_in, const int* in_sizes, int n_in,
                              void* d_out, int out_size, void* d_ws, size_t ws_size,
                              hipStream_t stream) {
  // Inputs f32 (verified by on-device probe in R5); output f32 (reference dtype).
  const float* x     = (const float*)d_in[0];
  const float* Wq    = (const float*)d_in[1];
  const float* Wkv   = (const float*)d_in[2];
  const float* Wproj = (const float*)d_in[3];
  const float* bproj = (const float*)d_in[4];
  const float* dwcw  = (const float*)d_in[5];
  const float* dwcb  = (const float*)d_in[6];
  const float* an    = (const float*)d_in[7];
  const float* na    = (const float*)d_in[8];
  const float* ahb   = (const float*)d_in[9];
  const float* awb   = (const float*)d_in[10];
  const float* adb   = (const float*)d_in[11];
  const float* hab   = (const float*)d_in[12];
  const float* wab   = (const float*)d_in[13];
  const float* dab   = (const float*)d_in[14];
  float* out = (float*)d_out;

  uint8_t* ws = (uint8_t*)d_ws;
  size_t off = 0;
  auto carve = [&](size_t elems) -> bf16* {
    bf16* p = (bf16*)(ws + off);
    off += ((elems * 2 + 255) & ~(size_t)255);
    return p;
  };
  bf16* wtall  = carve((size_t)1152 * 384);
  bf16* wprojT = carve((size_t)384 * 384);
  bf16* qb     = carve((size_t)MTOT * 384 + 128);
  bf16* kb     = carve((size_t)MTOT * 384 + 128);   // bias2 aliases after attn1
  bf16* vb     = carve((size_t)MTOT * 384 + 128);   // stays live (dwc reads it)
  bf16* vTb    = carve((size_t)MTOT * 384 + 128);
  bf16* adla   = carve((size_t)BATCH * ADLA_N * 384 + 128);
  bf16* advT   = carve((size_t)64 * 48 * ADV_W + 128);
  bf16* bias1  = carve((size_t)8 * ADLA_N * B1W);
  bf16* aout   = carve((size_t)MTOT * 384 + 128);   // own buffer (vb must stay live)
  bf16* bias2  = kb;   // kb dead after attn1

  transpose_weights<<<dim3((1152 * 384 + 384 * 384 + 255) / 256), 256, 0, stream>>>(
      Wq, Wkv, Wproj, wtall, wprojT);
  bias1_kernel<<<dim3(8 * ADLA_N), 256, 0, stream>>>(an, ahb, awb, adb, bias1);
  gemm128<0, float, bf16><<<dim3(172, 9), 256, 0, stream>>>(
      x, wtall, MTOT, qb, kb, vb, nullptr);
  transpose_v<<<dim3(43, 6, 8), 256, 0, stream>>>(vb, vTb);
  pool_kernel<<<dim3((BATCH * ADLA_N * DIM + 255) / 256), 256, 0, stream>>>(qb, adla);
  attn_kernel<<<dim3(6, 64), 256, 0, stream>>>(
      adla, kb, vTb, bias1, advT,
      ADLA_N, NTOK, B1W, (size_t)384 * NTOK, (size_t)48 * NTOK, NTOK, 0);
  bias2_kernel<<<dim3((int)(((size_t)8 * NTOK * B2W + 255) / 256)), 256, 0, stream>>>(
      na, hab, wab, dab, bias2);
  attn_kernel<<<dim3(43, 64), 256, 0, stream>>>(
      qb, adla, advT, bias2, aout,
      NTOK, ADLA_N, B2W, (size_t)8 * 48 * ADV_W, (size_t)48 * ADV_W, ADV_W, 1);
  dwc_kernel<<<dim3(86, 6, 8), 256, 0, stream>>>(vb, dwcw, dwcb, aout);
  gemm128<1, bf16, float><<<dim3(172, 3), 256, 0, stream>>>(
      aout, wprojT, MTOT, out, nullptr, nullptr, bproj);
}

// Round 8
// 667.938 us; speedup vs baseline: 1.1801x; 1.1131x over previous
//
#include <hip/hip_runtime.h>
#include <hip/hip_bf16.h>
#include <cstdint>

typedef __bf16 bf16;
typedef __attribute__((ext_vector_type(8))) __bf16 bf16x8;
typedef __attribute__((ext_vector_type(4))) float f32x4;

constexpr int DIM = 384;
constexpr int HEAD_DIM = 48;
constexpr int ADLA_N = 343;
constexpr int NTOK = 2744;        // 14^3
constexpr int BATCH = 8;
constexpr int MTOT = BATCH * NTOK; // 21952
constexpr float SCALE = 0.14433756729740643f; // 48^-0.5
constexpr int B1W = 2816;          // bias1 padded width (22*128)
constexpr int B2W = 384;           // bias2 padded width (3*128)
constexpr int ADV_W = 352;         // adla_v^T padded cols
constexpr int SEG = 6;             // attn1 column-split segments (4 chunks each)

// ---------------- weight transpose (f32 in -> bf16 out) -------------------------
__global__ void transpose_weights(const float* __restrict__ Wq,
                                  const float* __restrict__ Wkv,
                                  const float* __restrict__ Wproj,
                                  bf16* __restrict__ WTall,
                                  bf16* __restrict__ WprojT) {
  int idx = blockIdx.x * 256 + threadIdx.x;
  const int total1 = 1152 * 384;
  if (idx < total1) {
    int j = idx / 384, k = idx % 384;
    WTall[idx] = (bf16)((j < 384) ? Wq[k * 384 + j] : Wkv[k * 768 + (j - 384)]);
  } else {
    int i2 = idx - total1;
    if (i2 < 384 * 384) {
      int j = i2 / 384, k = i2 % 384;
      WprojT[i2] = (bf16)Wproj[k * 384 + j];
    }
  }
}

// ---------------- trilinear interp helpers (out 14 from in 7) ------------------
__device__ __forceinline__ void lin_w(int i, int& i0, int& i1, float& w) {
  float f = 0.5f * (float)i - 0.25f;
  f = fminf(fmaxf(f, 0.0f), 6.0f);
  i0 = (int)f;
  w = f - (float)i0;
  i1 = (i0 + 1 < 7) ? i0 + 1 : 6;
}

__device__ __forceinline__ float interp3(const float* __restrict__ p, int x, int y, int z) {
  int x0, x1, y0, y1, z0, z1; float wx, wy, wz;
  lin_w(x, x0, x1, wx); lin_w(y, y0, y1, wy); lin_w(z, z0, z1, wz);
  float c000 = p[x0*49 + y0*7 + z0], c001 = p[x0*49 + y0*7 + z1];
  float c010 = p[x0*49 + y1*7 + z0], c011 = p[x0*49 + y1*7 + z1];
  float c100 = p[x1*49 + y0*7 + z0], c101 = p[x1*49 + y0*7 + z1];
  float c110 = p[x1*49 + y1*7 + z0], c111 = p[x1*49 + y1*7 + z1];
  float c00 = c000 + wz * (c001 - c000), c01 = c010 + wz * (c011 - c010);
  float c10 = c100 + wz * (c101 - c100), c11 = c110 + wz * (c111 - c110);
  float c0 = c00 + wy * (c01 - c00), c1 = c10 + wy * (c11 - c10);
  return c0 + wx * (c1 - c0);
}

// ---------------- bias1[h][a][B1W] = interp(an)[h,a,n] + ah[x]+aw[y]+ad[z] ------
__global__ void bias1_kernel(const float* __restrict__ an, const float* __restrict__ ah,
                             const float* __restrict__ aw, const float* __restrict__ ad,
                             bf16* __restrict__ out) {
  int h = blockIdx.x / ADLA_N, a = blockIdx.x % ADLA_N;
  const float* anp = an + ((size_t)h * ADLA_N + a) * 343;
  const float* ahp = ah + ((size_t)h * ADLA_N + a) * 14;
  const float* awp = aw + ((size_t)h * ADLA_N + a) * 14;
  const float* adp = ad + ((size_t)h * ADLA_N + a) * 14;
  bf16* op = out + ((size_t)h * ADLA_N + a) * B1W;
  for (int n = threadIdx.x; n < B1W; n += 256) {
    if (n < NTOK) {
      int x = n / 196, y = (n / 14) % 14, z = n % 14;
      float v = interp3(anp, x, y, z) + ahp[x] + awp[y] + adp[z];
      op[n] = (bf16)v;
    } else {
      op[n] = (bf16)0.f;   // finite zero pad (read by attn1, masked)
    }
  }
}

// ---------------- bias2[h][n][B2W] = interp(na)[h,a,n] + ha[x,a]+wa[y,a]+da[z,a] -
__global__ void bias2_kernel(const float* __restrict__ na, const float* __restrict__ ha,
                             const float* __restrict__ wa, const float* __restrict__ da,
                             bf16* __restrict__ out) {
  size_t idx = (size_t)blockIdx.x * 256 + threadIdx.x;
  if (idx >= (size_t)8 * NTOK * B2W) return;
  int a = (int)(idx % B2W);
  int n = (int)((idx / B2W) % NTOK);
  int h = (int)(idx / ((size_t)B2W * NTOK));
  if (a >= ADLA_N) { out[idx] = (bf16)0.f; return; }  // finite zero pad
  int x = n / 196, y = (n / 14) % 14, z = n % 14;
  const float* nap = na + ((size_t)h * ADLA_N + a) * 343;
  float v = interp3(nap, x, y, z)
          + ha[((size_t)h * 14 + x) * ADLA_N + a]
          + wa[((size_t)h * 14 + y) * ADLA_N + a]
          + da[((size_t)h * 14 + z) * ADLA_N + a];
  out[idx] = (bf16)v;
}

// ---------------- 128x128 MFMA GEMM, K=384, B^T (bf16) --------------------------
// LDS stride padded 32->40 elements: fragment reads go 8-way -> 2-way conflicts.
template <int MODE, typename AT, typename OT>
__global__ __launch_bounds__(256)
void gemm128(const AT* __restrict__ A, const bf16* __restrict__ BT, int M,
             OT* __restrict__ O0, bf16* __restrict__ O1, bf16* __restrict__ O2,
             const float* __restrict__ bias) {
  __shared__ __align__(16) bf16 As[128 * 40];
  __shared__ __align__(16) bf16 Bs[128 * 40];
  const int tid = threadIdx.x;
  const int wv = tid >> 6, lane = tid & 63;
  const int m0 = blockIdx.x * 128, n0 = blockIdx.y * 128;
  const int wr = wv >> 1, wc = wv & 1;
  f32x4 zero4 = {0.f, 0.f, 0.f, 0.f};
  f32x4 acc[4][4];
#pragma unroll
  for (int i = 0; i < 4; i++)
#pragma unroll
    for (int j = 0; j < 4; j++) acc[i][j] = zero4;

  for (int k0 = 0; k0 < 384; k0 += 32) {
    __syncthreads();
#pragma unroll
    for (int i = 0; i < 2; i++) {
      int flat = i * 256 + tid;
      int row = flat >> 2, cg = flat & 3;
      int gr = m0 + row; if (gr >= M) gr = M - 1;
      bf16x8 av;
      if constexpr (sizeof(AT) == 4) {
        const float4* s4 = (const float4*)(A + (size_t)gr * 384 + k0 + cg * 8);
        float4 a = s4[0], b = s4[1];
        av[0]=(bf16)a.x; av[1]=(bf16)a.y; av[2]=(bf16)a.z; av[3]=(bf16)a.w;
        av[4]=(bf16)b.x; av[5]=(bf16)b.y; av[6]=(bf16)b.z; av[7]=(bf16)b.w;
      } else {
        av = *(const bf16x8*)(A + (size_t)gr * 384 + k0 + cg * 8);
      }
      *(bf16x8*)(As + row * 40 + cg * 8) = av;
      int nr = n0 + row;
      *(bf16x8*)(Bs + row * 40 + cg * 8) = *(const bf16x8*)(BT + (size_t)nr * 384 + k0 + cg * 8);
    }
    __syncthreads();
    bf16x8 af[4], bfr[4];
#pragma unroll
    for (int t = 0; t < 4; t++) {
      af[t]  = *(const bf16x8*)(As + (wr * 64 + t * 16 + (lane & 15)) * 40 + (lane >> 4) * 8);
      bfr[t] = *(const bf16x8*)(Bs + (wc * 64 + t * 16 + (lane & 15)) * 40 + (lane >> 4) * 8);
    }
#pragma unroll
    for (int rt = 0; rt < 4; rt++)
#pragma unroll
      for (int ct = 0; ct < 4; ct++)
        acc[rt][ct] = __builtin_amdgcn_mfma_f32_16x16x32_bf16(af[rt], bfr[ct], acc[rt][ct], 0, 0, 0);
  }
  const int quad = lane >> 4, colL = lane & 15;
#pragma unroll
  for (int rt = 0; rt < 4; rt++) {
#pragma unroll
    for (int ct = 0; ct < 4; ct++) {
      int gcol = n0 + wc * 64 + ct * 16 + colL;
#pragma unroll
      for (int r = 0; r < 4; r++) {
        int grow = m0 + wr * 64 + rt * 16 + quad * 4 + r;
        if (grow < M) {
          float v = acc[rt][ct][r];
          if (MODE == 1) {
            v += bias[gcol];
            O0[(size_t)grow * 384 + gcol] = (OT)v;   // OT=float for final output
          } else {
            bf16* dst; int c;
            if (gcol < 384)      { dst = (bf16*)O0; c = gcol; }
            else if (gcol < 768) { dst = O1; c = gcol - 384; }
            else                 { dst = O2; c = gcol - 768; }
            dst[(size_t)grow * 384 + c] = (bf16)v;
          }
        }
      }
    }
  }
}

// ---------------- v -> vT  ([b][n][c] -> [b][c][n]) -----------------------------
__global__ void transpose_v(const bf16* __restrict__ v, bf16* __restrict__ vT) {
  __shared__ bf16 t[64][65];
  int n0 = blockIdx.x * 64, c0 = blockIdx.y * 64, b = blockIdx.z;
  int tid = threadIdx.x;
  int cl = tid & 63, rs = tid >> 6;
  for (int j = 0; j < 16; j++) {
    int r = rs * 16 + j;
    int n = n0 + r;
    if (n < NTOK) t[cl][r] = v[((size_t)b * NTOK + n) * DIM + c0 + cl];
  }
  __syncthreads();
  int nl = tid & 63, cs = tid >> 6;
  int n = n0 + nl;
  if (n < NTOK)
    for (int j = 0; j < 16; j++) {
      int cc = cs * 16 + j;
      vT[((size_t)b * DIM + c0 + cc) * NTOK + n] = t[cc][nl];
    }
}

// ---------------- 2x2x2 mean-pool of q -> adla [b][343][384] --------------------
__global__ void pool_kernel(const bf16* __restrict__ q, bf16* __restrict__ adla) {
  int idx = blockIdx.x * 256 + threadIdx.x;
  if (idx >= BATCH * ADLA_N * DIM) return;
  int c = idx % DIM;
  int a = (idx / DIM) % ADLA_N;
  int b = idx / (DIM * ADLA_N);
  int a0 = a / 49, a1 = (a / 7) % 7, a2 = a % 7;
  float s = 0.f;
#pragma unroll
  for (int i = 0; i < 2; i++)
#pragma unroll
    for (int j = 0; j < 2; j++)
#pragma unroll
      for (int k = 0; k < 2; k++) {
        int n = (a0 * 2 + i) * 196 + (a1 * 2 + j) * 14 + (a2 * 2 + k);
        s += (float)q[((size_t)b * NTOK + n) * DIM + c];
      }
  adla[idx] = (bf16)(s * 0.125f);
}

// ---------------- unified no-max streaming attention (bf16 internals) -----------
// XOR-swizzled LDS (chunk cg stored at cg^(row&mask)) kills 16-way bank conflicts
// without growing LDS (53 KB -> 3 blocks/CU preserved).
// MODE 0 (attn1, column-split): blockIdx.z = segment of 4 column-chunks; writes
//   f32 partial O (un-normalized) to OutP[seg][bh][48][ADV_W] and partial
//   rowsums to RsP[seg][bh][ADV_W]. attn1_reduce normalizes.
// MODE 1 (attn2): full column range; normalized bf16 row-major output.
template <int MODE>
__global__ __launch_bounds__(256)
void attn_kernel(const bf16* __restrict__ Amat, const bf16* __restrict__ Kmat,
                 const bf16* __restrict__ Vt, const bf16* __restrict__ Bias,
                 bf16* __restrict__ Out, float* __restrict__ OutP,
                 float* __restrict__ RsP,
                 int AR, int NC, int biasW,
                 size_t vtB, size_t vtH, int vtS) {
  __shared__ __align__(16) bf16 aT[64 * 64];
  __shared__ __align__(16) bf16 kT[128 * 64];
  __shared__ __align__(16) bf16 vTs[48 * 128];
  __shared__ __align__(16) bf16 pT[64 * 128];
  const int tid = threadIdx.x;
  const int wv = tid >> 6, lane = tid & 63;
  const int bh = blockIdx.y;
  const int bI = bh >> 3, h = bh & 7;
  const int r0 = blockIdx.x * 64;
  const int quad = lane >> 4, colL = lane & 15;

  // A tile [64][64], zero-padded in k (cols 48..63), rows clamped, swizzled
#pragma unroll
  for (int i = 0; i < 2; i++) {
    int flat = i * 256 + tid;
    int row = flat >> 3, cg = flat & 7;
    int r = r0 + row; if (r >= AR) r = AR - 1;
    bf16x8 val;
#pragma unroll
    for (int e = 0; e < 8; e++) val[e] = (bf16)0.f;
    if (cg < 6) val = *(const bf16x8*)(Amat + ((size_t)bI * AR + r) * DIM + h * HEAD_DIM + cg * 8);
    *(bf16x8*)(aT + row * 64 + ((cg ^ (row & 7)) << 3)) = val;
  }

  f32x4 zero4 = {0.f, 0.f, 0.f, 0.f};
  f32x4 acc[3] = {zero4, zero4, zero4};
  float rowsum[4] = {0.f, 0.f, 0.f, 0.f};
  const int nCh = (NC + 127) >> 7;
  const int ch0 = blockIdx.z * 4;
  const int ch1 = min(nCh, ch0 + 4);

  for (int ch = ch0; ch < ch1; ch++) {
    const int c0 = ch << 7;
    __syncthreads();
    // K tile [128][64]; k-cols 48..63 finite dup of 0..15 (A zero there); swizzled
#pragma unroll
    for (int i = 0; i < 4; i++) {
      int flat = i * 256 + tid;
      int row = flat >> 3, cg = flat & 7;
      int kg = (cg < 6) ? cg : 0;
      int gr = c0 + row; if (gr >= NC) gr = NC - 1;
      *(bf16x8*)(kT + row * 64 + ((cg ^ (row & 7)) << 3)) =
          *(const bf16x8*)(Kmat + ((size_t)bI * NC + gr) * DIM + h * HEAD_DIM + kg * 8);
    }
    // V^T tile [48][128]; column-clamped to stay in written memory; swizzled
#pragma unroll
    for (int i = 0; i < 3; i++) {
      int flat = i * 256 + tid;
      int d = flat >> 4, cg = flat & 15;
      int cc = c0 + cg * 8; if (cc > vtS - 8) cc = vtS - 8;
      *(bf16x8*)(vTs + d * 128 + ((cg ^ (d & 15)) << 3)) =
          *(const bf16x8*)(Vt + (size_t)bI * vtB + (size_t)h * vtH + (size_t)d * vtS + cc);
    }
    // Bias tile -> pT [64][128], swizzled
#pragma unroll
    for (int i = 0; i < 4; i++) {
      int flat = i * 256 + tid;
      int row = flat >> 4, cg = flat & 15;
      int r = r0 + row; if (r >= AR) r = AR - 1;
      *(bf16x8*)(pT + row * 128 + ((cg ^ (row & 15)) << 3)) =
          *(const bf16x8*)(Bias + ((size_t)h * AR + r) * biasW + c0 + cg * 8);
    }
    __syncthreads();

    // S phase
    const int arow = wv * 16 + colL;
    bf16x8 af0 = *(const bf16x8*)(aT + arow * 64 + ((quad ^ (arow & 7)) << 3));
    bf16x8 af1 = *(const bf16x8*)(aT + arow * 64 + (((4 | quad) ^ (arow & 7)) << 3));
    f32x4 sacc[8];
#pragma unroll
    for (int ct = 0; ct < 8; ct++) sacc[ct] = zero4;
#pragma unroll
    for (int ct = 0; ct < 8; ct++) {
      int krow = ct * 16 + colL;
      bf16x8 b0 = *(const bf16x8*)(kT + krow * 64 + ((quad ^ (krow & 7)) << 3));
      bf16x8 b1 = *(const bf16x8*)(kT + krow * 64 + (((4 | quad) ^ (krow & 7)) << 3));
      sacc[ct] = __builtin_amdgcn_mfma_f32_16x16x32_bf16(af0, b0, sacc[ct], 0, 0, 0);
      sacc[ct] = __builtin_amdgcn_mfma_f32_16x16x32_bf16(af1, b1, sacc[ct], 0, 0, 0);
    }
    // bias + exp -> P back into pT (swizzled element addressing)
#pragma unroll
    for (int ct = 0; ct < 8; ct++) {
      int c = ct * 16 + colL;
      bool valid = (c0 + c) < NC;
#pragma unroll
      for (int r = 0; r < 4; r++) {
        int row = wv * 16 + quad * 4 + r;
        int pos = row * 128 + (((c >> 3) ^ (row & 15)) << 3) + (c & 7);
        float s = sacc[ct][r] * SCALE + (float)pT[pos];
        s = fminf(fmaxf(s, -60.f), 60.f);
        float p = valid ? __expf(s) : 0.f;
        rowsum[r] += p;
        pT[pos] = (bf16)p;
      }
    }
    // PV phase: acc += P @ V^T (K = 128)
#pragma unroll
    for (int ks = 0; ks < 4; ks++) {
      const int prow = wv * 16 + colL;
      bf16x8 pf = *(const bf16x8*)(pT + prow * 128 + (((ks * 4 + quad) ^ (prow & 15)) << 3));
#pragma unroll
      for (int dt = 0; dt < 3; dt++) {
        const int vrow = dt * 16 + colL;
        bf16x8 vf = *(const bf16x8*)(vTs + vrow * 128 + (((ks * 4 + quad) ^ (vrow & 15)) << 3));
        acc[dt] = __builtin_amdgcn_mfma_f32_16x16x32_bf16(pf, vf, acc[dt], 0, 0, 0);
      }
    }
  }

  // rowsum reduce over the 16 col-lanes within each quad
#pragma unroll
  for (int m = 1; m < 16; m <<= 1)
#pragma unroll
    for (int r = 0; r < 4; r++) rowsum[r] += __shfl_xor(rowsum[r], m, 64);

  if (MODE == 0) {
    const int seg = blockIdx.z;
#pragma unroll
    for (int dt = 0; dt < 3; dt++)
#pragma unroll
      for (int r = 0; r < 4; r++) {
        int a = r0 + wv * 16 + quad * 4 + r;
        size_t rowD = ((size_t)seg * 64 + bh) * 48 + dt * 16 + colL;
        if (a < AR)
          OutP[rowD * ADV_W + a] = acc[dt][r];
        else if (a < ADV_W)
          OutP[rowD * ADV_W + a] = 0.f;   // identical zero from all segs: benign
      }
    if (colL == 0) {
#pragma unroll
      for (int r = 0; r < 4; r++) {
        int a = r0 + wv * 16 + quad * 4 + r;
        if (a < AR)
          RsP[((size_t)seg * 64 + bh) * ADV_W + a] = rowsum[r];
      }
    }
  } else {
    float inv[4];
#pragma unroll
    for (int r = 0; r < 4; r++) inv[r] = 1.f / rowsum[r];
#pragma unroll
    for (int dt = 0; dt < 3; dt++)
#pragma unroll
      for (int r = 0; r < 4; r++) {
        int n = r0 + wv * 16 + quad * 4 + r;
        if (n < AR)
          Out[((size_t)bI * AR + n) * DIM + h * HEAD_DIM + dt * 16 + colL] = (bf16)(acc[dt][r] * inv[r]);
      }
  }
}

// ---------------- attn1 partial reduce: advT = sum(advP)/sum(rsP) ---------------
__global__ void attn1_reduce(const float* __restrict__ advP, const float* __restrict__ rsP,
                             bf16* __restrict__ advT) {
  int idx = blockIdx.x * 256 + threadIdx.x;
  if (idx >= 64 * 48 * ADV_W) return;
  int a = idx % ADV_W;
  int d = (idx / ADV_W) % 48;
  int bh = idx / (ADV_W * 48);
  if (a >= ADLA_N) { advT[idx] = (bf16)0.f; return; }
  float s = 0.f, rs = 0.f;
#pragma unroll
  for (int g = 0; g < SEG; g++) {
    s  += advP[(((size_t)g * 64 + bh) * 48 + d) * ADV_W + a];
    rs += rsP[((size_t)g * 64 + bh) * ADV_W + a];
  }
  advT[((size_t)bh * 48 + d) * ADV_W + a] = (bf16)(s / rs);
}

// ---------------- depthwise 3x3x3 conv, lane=channel, RMW-add into io -----------
__global__ __launch_bounds__(256)
void dwc_kernel(const bf16* __restrict__ v, const float* __restrict__ w,
                const float* __restrict__ bias, bf16* __restrict__ io) {
  const int tid = threadIdx.x;
  const int lane = tid & 63, wv = tid >> 6;
  const int c = blockIdx.y * 64 + lane;
  const int b = blockIdx.z;
  const int n_base = blockIdx.x * 32 + wv * 8;
  float wt[27];
#pragma unroll
  for (int t = 0; t < 27; t++) wt[t] = w[c * 27 + t];
  const float bs = bias[c];
  const bf16* vb_ = v + (size_t)b * NTOK * DIM;
  bf16* iob = io + (size_t)b * NTOK * DIM;
#pragma unroll
  for (int k = 0; k < 8; k++) {
    int n = n_base + k;
    if (n >= NTOK) break;
    int x = n / 196, y = (n / 14) % 14, z = n % 14;
    float s = bs;
#pragma unroll
    for (int dx = -1; dx <= 1; dx++) {
      int X = x + dx; if ((unsigned)X >= 14u) continue;
#pragma unroll
      for (int dy = -1; dy <= 1; dy++) {
        int Y = y + dy; if ((unsigned)Y >= 14u) continue;
#pragma unroll
        for (int dz = -1; dz <= 1; dz++) {
          int Z = z + dz; if ((unsigned)Z >= 14u) continue;
          s += (float)vb_[(size_t)(X * 196 + Y * 14 + Z) * DIM + c]
             * wt[(dx + 1) * 9 + (dy + 1) * 3 + (dz + 1)];
        }
      }
    }
    size_t idx = (size_t)n * DIM + c;
    iob[idx] = (bf16)((float)iob[idx] + s);
  }
}

// -------------------------------------------------------------------------------
extern "C" void kernel_launch(void* const* d_in, const int* in_sizes, int n_in,
                              void* d_out, int out_size, void* d_ws, size_t ws_size,
                              hipStream_t stream) {
  const float* x     = (const float*)d_in[0];
  const float* Wq    = (const float*)d_in[1];
  const float* Wkv   = (const float*)d_in[2];
  const float* Wproj = (const float*)d_in[3];
  const float* bproj = (const float*)d_in[4];
  const float* dwcw  = (const float*)d_in[5];
  const float* dwcb  = (const float*)d_in[6];
  const float* an    = (const float*)d_in[7];
  const float* na    = (const float*)d_in[8];
  const float* ahb   = (const float*)d_in[9];
  const float* awb   = (const float*)d_in[10];
  const float* adb   = (const float*)d_in[11];
  const float* hab   = (const float*)d_in[12];
  const float* wab   = (const float*)d_in[13];
  const float* dab   = (const float*)d_in[14];
  float* out = (float*)d_out;

  uint8_t* ws = (uint8_t*)d_ws;
  size_t off = 0;
  auto carveB = [&](size_t bytes) -> void* {
    void* p = ws + off;
    off += ((bytes + 255) & ~(size_t)255);
    return p;
  };
  auto carve = [&](size_t elems) -> bf16* { return (bf16*)carveB(elems * 2); };
  bf16*  wtall  = carve((size_t)1152 * 384);
  bf16*  wprojT = carve((size_t)384 * 384);
  bf16*  qb     = carve((size_t)MTOT * 384 + 128);
  bf16*  kb     = carve((size_t)MTOT * 384 + 128);   // bias2 aliases after attn1
  bf16*  vb     = carve((size_t)MTOT * 384 + 128);   // live until dwc
  bf16*  vTb    = carve((size_t)MTOT * 384 + 128);   // dead after attn1 -> aout aliases
  bf16*  adla   = carve((size_t)BATCH * ADLA_N * 384 + 128);
  bf16*  advT   = carve((size_t)64 * 48 * ADV_W + 128);
  bf16*  bias1  = carve((size_t)8 * ADLA_N * B1W);
  float* advP   = (float*)carveB((size_t)SEG * 64 * 48 * ADV_W * 4);
  float* rsP    = (float*)carveB((size_t)SEG * 64 * ADV_W * 4);
  bf16*  bias2  = kb;    // kb dead after attn1
  bf16*  aout   = vTb;   // vTb dead after attn1

  transpose_weights<<<dim3((1152 * 384 + 384 * 384 + 255) / 256), 256, 0, stream>>>(
      Wq, Wkv, Wproj, wtall, wprojT);
  bias1_kernel<<<dim3(8 * ADLA_N), 256, 0, stream>>>(an, ahb, awb, adb, bias1);
  gemm128<0, float, bf16><<<dim3(172, 9), 256, 0, stream>>>(
      x, wtall, MTOT, qb, kb, vb, nullptr);
  transpose_v<<<dim3(43, 6, 8), 256, 0, stream>>>(vb, vTb);
  pool_kernel<<<dim3((BATCH * ADLA_N * DIM + 255) / 256), 256, 0, stream>>>(qb, adla);
  attn_kernel<0><<<dim3(6, 64, SEG), 256, 0, stream>>>(
      adla, kb, vTb, bias1, nullptr, advP, rsP,
      ADLA_N, NTOK, B1W, (size_t)384 * NTOK, (size_t)48 * NTOK, NTOK);
  attn1_reduce<<<dim3((64 * 48 * ADV_W + 255) / 256), 256, 0, stream>>>(advP, rsP, advT);
  bias2_kernel<<<dim3((int)(((size_t)8 * NTOK * B2W + 255) / 256)), 256, 0, stream>>>(
      na, hab, wab, dab, bias2);
  attn_kernel<1><<<dim3(43, 64, 1), 256, 0, stream>>>(
      qb, adla, advT, bias2, aout, nullptr, nullptr,
      NTOK, ADLA_N, B2W, (size_t)8 * 48 * ADV_W, (size_t)48 * ADV_W, ADV_W);
  dwc_kernel<<<dim3(86, 6, 8), 256, 0, stream>>>(vb, dwcw, dwcb, aout);
  gemm128<1, bf16, float><<<dim3(172, 3), 256, 0, stream>>>(
      aout, wprojT, MTOT, out, nullptr, nullptr, bproj);
}